// Round 1
// baseline (909.998 us; speedup 1.0000x reference)
//
#include <hip/hip_runtime.h>

// Static device scratch: N*256 floats @ N=100000 -> 102.4 MB.
// Layout (float offsets, N = #nodes):
//   agg1 : [0,        N*32)
//   agg2 : [N*32,     N*80)
//   t1   : [N*80,     N*112)
//   r1   : [N*112,    N*144)
//   t2   : [N*144,    N*192)
//   r2   : [N*192,    N*240)
//   t3   : [N*240,    N*256)
#define NODES_MAX 100000
__device__ float g_ws[(size_t)NODES_MAX * 256];

__global__ __launch_bounds__(256) void k_zero(size_t n) {
    size_t i = (size_t)blockIdx.x * 256 + threadIdx.x;
    if (i < n) g_ws[i] = 0.f;
}

// Layer 1 transform: h0 = concat(x[48], ax[16]); t1 = h0@W1_rel; r1 = h0@W1_root + b1
__global__ __launch_bounds__(256) void k_l1_transform(
        const float* __restrict__ x, const float* __restrict__ ax,
        const float* __restrict__ Wrel, const float* __restrict__ Wroot,
        const float* __restrict__ b, int N, size_t oT1, size_t oR1) {
    __shared__ float sWrel[64 * 32];
    __shared__ float sWroot[64 * 32];
    __shared__ float sH[8 * 64];
    const int tid = threadIdx.x;
    for (int i = tid; i < 64 * 32; i += 256) { sWrel[i] = Wrel[i]; sWroot[i] = Wroot[i]; }
    const int n0 = blockIdx.x * 8;
    for (int i = tid; i < 8 * 64; i += 256) {
        int nl = i >> 6, k = i & 63, n = n0 + nl;
        float v = 0.f;
        if (n < N) v = (k < 48) ? x[(size_t)n * 48 + k] : ax[(size_t)n * 16 + (k - 48)];
        sH[i] = v;
    }
    __syncthreads();
    const int nl = tid >> 5, j = tid & 31, n = n0 + nl;
    if (n < N) {
        float at = 0.f, ar = 0.f;
        #pragma unroll
        for (int k = 0; k < 64; ++k) {
            float h = sH[nl * 64 + k];
            at = fmaf(h, sWrel[k * 32 + j], at);
            ar = fmaf(h, sWroot[k * 32 + j], ar);
        }
        g_ws[oT1 + (size_t)n * 32 + j] = at;
        g_ws[oR1 + (size_t)n * 32 + j] = ar + b[j];
    }
}

// Layer 2 transform: h1c = concat(relu(agg1+r1)[32], lf[16]); t2/r2 = h1c @ W2_{rel,root} (+b2)
__global__ __launch_bounds__(384) void k_l2_transform(
        const float* __restrict__ lf,
        const float* __restrict__ Wrel, const float* __restrict__ Wroot,
        const float* __restrict__ b, int N,
        size_t oAgg1, size_t oR1, size_t oT2, size_t oR2) {
    __shared__ float sWrel[48 * 48];
    __shared__ float sWroot[48 * 48];
    __shared__ float sH[8 * 48];
    const int tid = threadIdx.x;
    for (int i = tid; i < 48 * 48; i += 384) { sWrel[i] = Wrel[i]; sWroot[i] = Wroot[i]; }
    const int n0 = blockIdx.x * 8;
    {
        int nl = tid / 48, k = tid % 48, n = n0 + nl;  // 384 == 8*48, one each
        float v = 0.f;
        if (n < N) {
            if (k < 32) {
                float a = g_ws[oAgg1 + (size_t)n * 32 + k] + g_ws[oR1 + (size_t)n * 32 + k];
                v = fmaxf(a, 0.f);
            } else {
                v = lf[(size_t)n * 16 + (k - 32)];
            }
        }
        sH[tid] = v;
    }
    __syncthreads();
    const int nl = tid / 48, j = tid % 48, n = n0 + nl;
    if (n < N) {
        float at = 0.f, ar = 0.f;
        #pragma unroll
        for (int k = 0; k < 48; ++k) {
            float h = sH[nl * 48 + k];
            at = fmaf(h, sWrel[k * 48 + j], at);
            ar = fmaf(h, sWroot[k * 48 + j], ar);
        }
        g_ws[oT2 + (size_t)n * 48 + j] = at;
        g_ws[oR2 + (size_t)n * 48 + j] = ar + b[j];
    }
}

// Layer 3 transform: h2 = relu(agg2+r2); t3 = h2@W3_rel; out = h2@W3_root + b3 + ax
__global__ __launch_bounds__(256) void k_l3_transform(
        const float* __restrict__ ax,
        const float* __restrict__ Wrel, const float* __restrict__ Wroot,
        const float* __restrict__ b, int N,
        size_t oAgg2, size_t oR2, size_t oT3, float* __restrict__ out) {
    __shared__ float sWrel[48 * 16];
    __shared__ float sWroot[48 * 16];
    __shared__ float sH[16 * 48];
    const int tid = threadIdx.x;
    for (int i = tid; i < 48 * 16; i += 256) { sWrel[i] = Wrel[i]; sWroot[i] = Wroot[i]; }
    const int n0 = blockIdx.x * 16;
    for (int i = tid; i < 16 * 48; i += 256) {
        int nl = i / 48, k = i % 48, n = n0 + nl;
        float v = 0.f;
        if (n < N) {
            float a = g_ws[oAgg2 + (size_t)n * 48 + k] + g_ws[oR2 + (size_t)n * 48 + k];
            v = fmaxf(a, 0.f);
        }
        sH[i] = v;
    }
    __syncthreads();
    const int nl = tid >> 4, j = tid & 15, n = n0 + nl;
    if (n < N) {
        float at = 0.f, ar = 0.f;
        #pragma unroll
        for (int k = 0; k < 48; ++k) {
            float h = sH[nl * 48 + k];
            at = fmaf(h, sWrel[k * 16 + j], at);
            ar = fmaf(h, sWroot[k * 16 + j], ar);
        }
        g_ws[oT3 + (size_t)n * 16 + j] = at;
        out[(size_t)n * 16 + j] = ar + b[j] + ax[(size_t)n * 16 + j];
    }
}

// Edge scatter kernels: one lane per (edge, feature). agg[dst*F+c] += t[src*F+c]
__global__ __launch_bounds__(256) void k_edge1(const int* __restrict__ edge, int E,
                                               size_t oT1, size_t oAgg1) {
    int t = blockIdx.x * 256 + threadIdx.x;
    int e = t >> 5, c = t & 31;
    if (e < E) {
        int s = edge[e], d = edge[E + e];
        atomicAdd(&g_ws[oAgg1 + (size_t)d * 32 + c], g_ws[oT1 + (size_t)s * 32 + c]);
    }
}

__global__ __launch_bounds__(256) void k_edge2(const int* __restrict__ edge, int E,
                                               size_t oT2, size_t oAgg2) {
    int t = blockIdx.x * 256 + threadIdx.x;
    int e = t / 48, c = t % 48;
    if (e < E) {
        int s = edge[e], d = edge[E + e];
        atomicAdd(&g_ws[oAgg2 + (size_t)d * 48 + c], g_ws[oT2 + (size_t)s * 48 + c]);
    }
}

__global__ __launch_bounds__(256) void k_edge3(const int* __restrict__ edge, int E,
                                               size_t oT3, float* __restrict__ out) {
    int t = blockIdx.x * 256 + threadIdx.x;
    int e = t >> 4, c = t & 15;
    if (e < E) {
        int s = edge[e], d = edge[E + e];
        atomicAdd(&out[(size_t)d * 16 + c], g_ws[oT3 + (size_t)s * 16 + c]);
    }
}

extern "C" void kernel_launch(void* const* d_in, const int* in_sizes, int n_in,
                              void* d_out, int out_size, void* d_ws, size_t ws_size,
                              hipStream_t stream) {
    const float* x     = (const float*)d_in[0];
    const int*   edge  = (const int*)d_in[1];
    const float* ax    = (const float*)d_in[2];
    const float* lf    = (const float*)d_in[3];
    const float* W1rel = (const float*)d_in[4];
    const float* b1    = (const float*)d_in[5];
    const float* W1root= (const float*)d_in[6];
    const float* W2rel = (const float*)d_in[7];
    const float* b2    = (const float*)d_in[8];
    const float* W2root= (const float*)d_in[9];
    const float* W3rel = (const float*)d_in[10];
    const float* b3    = (const float*)d_in[11];
    const float* W3root= (const float*)d_in[12];
    float* out = (float*)d_out;

    const int N = in_sizes[0] / 48;
    const int E = in_sizes[1] / 2;

    const size_t oAgg1 = 0;
    const size_t oAgg2 = (size_t)N * 32;
    const size_t oT1   = (size_t)N * 80;
    const size_t oR1   = (size_t)N * 112;
    const size_t oT2   = (size_t)N * 144;
    const size_t oR2   = (size_t)N * 192;
    const size_t oT3   = (size_t)N * 240;

    const size_t zn = (size_t)N * 80;  // agg1 + agg2 contiguous
    k_zero<<<(unsigned)((zn + 255) / 256), 256, 0, stream>>>(zn);

    k_l1_transform<<<(N + 7) / 8, 256, 0, stream>>>(x, ax, W1rel, W1root, b1, N, oT1, oR1);
    k_edge1<<<(unsigned)(((size_t)E * 32 + 255) / 256), 256, 0, stream>>>(edge, E, oT1, oAgg1);
    k_l2_transform<<<(N + 7) / 8, 384, 0, stream>>>(lf, W2rel, W2root, b2, N, oAgg1, oR1, oT2, oR2);
    k_edge2<<<(unsigned)(((size_t)E * 48 + 255) / 256), 256, 0, stream>>>(edge, E, oT2, oAgg2);
    k_l3_transform<<<(N + 15) / 16, 256, 0, stream>>>(ax, W3rel, W3root, b3, N, oAgg2, oR2, oT3, out);
    k_edge3<<<(unsigned)(((size_t)E * 16 + 255) / 256), 256, 0, stream>>>(edge, E, oT3, out);
}

// Round 2
// 747.344 us; speedup vs baseline: 1.2176x; 1.2176x over previous
//
#include <hip/hip_runtime.h>

#define NODES_MAX 100000
#define EDGES_MAX 1600000

// Float scratch: N*256 floats @ N=100000 -> 102.4 MB
// layout (float offsets): t1:0  r1:N*32  h1:N*64  t2:N*96  r2:N*144  h2:N*192  t3:N*240
__device__ float g_ws[(size_t)NODES_MAX * 256];
__device__ int g_rowptr[NODES_MAX + 1];
__device__ int g_cnt[NODES_MAX];      // deg -> cursor
__device__ int g_csr[EDGES_MAX];      // src node id grouped by dst

// ---------------- CSR build ----------------
__global__ __launch_bounds__(256) void k_zero_cnt(int N) {
    int i = blockIdx.x * 256 + threadIdx.x;
    if (i < N) g_cnt[i] = 0;
}

__global__ __launch_bounds__(256) void k_hist(const int* __restrict__ edge, int E) {
    int e = blockIdx.x * 256 + threadIdx.x;
    if (e < E) atomicAdd(&g_cnt[edge[E + e]], 1);
}

#define SCAN_T 1024
__global__ __launch_bounds__(SCAN_T) void k_scan(int N) {
    __shared__ int ssum[SCAN_T];
    const int tid = threadIdx.x;
    const int chunk = (N + SCAN_T - 1) / SCAN_T;
    const int lo = min(tid * chunk, N);
    const int hi = min(lo + chunk, N);
    int s = 0;
    for (int i = lo; i < hi; ++i) s += g_cnt[i];
    ssum[tid] = s;
    __syncthreads();
    for (int off = 1; off < SCAN_T; off <<= 1) {
        int v = (tid >= off) ? ssum[tid - off] : 0;
        __syncthreads();
        ssum[tid] += v;
        __syncthreads();
    }
    int run = ssum[tid] - s;  // exclusive prefix of this thread's chunk
    for (int i = lo; i < hi; ++i) {
        int d = g_cnt[i];
        g_rowptr[i] = run;
        g_cnt[i] = run;       // cursor init
        run += d;
    }
    if (tid == SCAN_T - 1) g_rowptr[N] = run;  // == E
}

__global__ __launch_bounds__(256) void k_scatter(const int* __restrict__ edge, int E) {
    int e = blockIdx.x * 256 + threadIdx.x;
    if (e < E) {
        int s = edge[e], d = edge[E + e];
        int pos = atomicAdd(&g_cnt[d], 1);
        g_csr[pos] = s;
    }
}

// ---------------- gathers ----------------
// h[node] = relu( sum_{in-edges} t[src] + r[node] )
template <int F>
__global__ __launch_bounds__(256) void k_gather_relu(size_t oT, size_t oR, size_t oH, int N) {
    constexpr int F4 = F / 4;
    int tid = blockIdx.x * 256 + threadIdx.x;
    int node = tid / F4, c4 = tid % F4;
    if (node >= N) return;
    const float* __restrict__ t = &g_ws[oT];
    int start = g_rowptr[node], end = g_rowptr[node + 1];
    float4 s = {0.f, 0.f, 0.f, 0.f};
    for (int j = start; j < end; ++j) {
        int sn = g_csr[j];
        const float4 v = *(const float4*)&t[(size_t)sn * F + c4 * 4];
        s.x += v.x; s.y += v.y; s.z += v.z; s.w += v.w;
    }
    const float4 rv = *(const float4*)&g_ws[oR + (size_t)node * F + c4 * 4];
    float4 o;
    o.x = fmaxf(s.x + rv.x, 0.f);
    o.y = fmaxf(s.y + rv.y, 0.f);
    o.z = fmaxf(s.z + rv.z, 0.f);
    o.w = fmaxf(s.w + rv.w, 0.f);
    *(float4*)&g_ws[oH + (size_t)node * F + c4 * 4] = o;
}

// out[node] += sum_{in-edges} t3[src]   (out pre-seeded with root+bias+ax)
__global__ __launch_bounds__(256) void k_gather_out(size_t oT, float* __restrict__ out, int N) {
    constexpr int F = 16, F4 = 4;
    int tid = blockIdx.x * 256 + threadIdx.x;
    int node = tid / F4, c4 = tid % F4;
    if (node >= N) return;
    const float* __restrict__ t = &g_ws[oT];
    int start = g_rowptr[node], end = g_rowptr[node + 1];
    float4 s = {0.f, 0.f, 0.f, 0.f};
    for (int j = start; j < end; ++j) {
        int sn = g_csr[j];
        const float4 v = *(const float4*)&t[(size_t)sn * F + c4 * 4];
        s.x += v.x; s.y += v.y; s.z += v.z; s.w += v.w;
    }
    float4* op = (float4*)&out[(size_t)node * F + c4 * 4];
    float4 ov = *op;
    ov.x += s.x; ov.y += s.y; ov.z += s.z; ov.w += s.w;
    *op = ov;
}

// ---------------- transforms ----------------
__global__ __launch_bounds__(256) void k_l1_transform(
        const float* __restrict__ x, const float* __restrict__ ax,
        const float* __restrict__ Wrel, const float* __restrict__ Wroot,
        const float* __restrict__ b, int N, size_t oT1, size_t oR1) {
    __shared__ float sWrel[64 * 32];
    __shared__ float sWroot[64 * 32];
    __shared__ float sH[8 * 64];
    const int tid = threadIdx.x;
    for (int i = tid; i < 64 * 32; i += 256) { sWrel[i] = Wrel[i]; sWroot[i] = Wroot[i]; }
    const int n0 = blockIdx.x * 8;
    for (int i = tid; i < 8 * 64; i += 256) {
        int nl = i >> 6, k = i & 63, n = n0 + nl;
        float v = 0.f;
        if (n < N) v = (k < 48) ? x[(size_t)n * 48 + k] : ax[(size_t)n * 16 + (k - 48)];
        sH[i] = v;
    }
    __syncthreads();
    const int nl = tid >> 5, j = tid & 31, n = n0 + nl;
    if (n < N) {
        float at = 0.f, ar = 0.f;
        #pragma unroll
        for (int k = 0; k < 64; ++k) {
            float h = sH[nl * 64 + k];
            at = fmaf(h, sWrel[k * 32 + j], at);
            ar = fmaf(h, sWroot[k * 32 + j], ar);
        }
        g_ws[oT1 + (size_t)n * 32 + j] = at;
        g_ws[oR1 + (size_t)n * 32 + j] = ar + b[j];
    }
}

__global__ __launch_bounds__(384) void k_l2_transform(
        const float* __restrict__ lf,
        const float* __restrict__ Wrel, const float* __restrict__ Wroot,
        const float* __restrict__ b, int N,
        size_t oH1, size_t oT2, size_t oR2) {
    __shared__ float sWrel[48 * 48];
    __shared__ float sWroot[48 * 48];
    __shared__ float sH[8 * 48];
    const int tid = threadIdx.x;
    for (int i = tid; i < 48 * 48; i += 384) { sWrel[i] = Wrel[i]; sWroot[i] = Wroot[i]; }
    const int n0 = blockIdx.x * 8;
    {
        int nl = tid / 48, k = tid % 48, n = n0 + nl;  // 384 == 8*48
        float v = 0.f;
        if (n < N) {
            v = (k < 32) ? g_ws[oH1 + (size_t)n * 32 + k]
                         : lf[(size_t)n * 16 + (k - 32)];
        }
        sH[tid] = v;
    }
    __syncthreads();
    const int nl = tid / 48, j = tid % 48, n = n0 + nl;
    if (n < N) {
        float at = 0.f, ar = 0.f;
        #pragma unroll
        for (int k = 0; k < 48; ++k) {
            float h = sH[nl * 48 + k];
            at = fmaf(h, sWrel[k * 48 + j], at);
            ar = fmaf(h, sWroot[k * 48 + j], ar);
        }
        g_ws[oT2 + (size_t)n * 48 + j] = at;
        g_ws[oR2 + (size_t)n * 48 + j] = ar + b[j];
    }
}

__global__ __launch_bounds__(256) void k_l3_transform(
        const float* __restrict__ ax,
        const float* __restrict__ Wrel, const float* __restrict__ Wroot,
        const float* __restrict__ b, int N,
        size_t oH2, size_t oT3, float* __restrict__ out) {
    __shared__ float sWrel[48 * 16];
    __shared__ float sWroot[48 * 16];
    __shared__ float sH[16 * 48];
    const int tid = threadIdx.x;
    for (int i = tid; i < 48 * 16; i += 256) { sWrel[i] = Wrel[i]; sWroot[i] = Wroot[i]; }
    const int n0 = blockIdx.x * 16;
    for (int i = tid; i < 16 * 48; i += 256) {
        int nl = i / 48, k = i % 48, n = n0 + nl;
        sH[i] = (n < N) ? g_ws[oH2 + (size_t)n * 48 + k] : 0.f;
    }
    __syncthreads();
    const int nl = tid >> 4, j = tid & 15, n = n0 + nl;
    if (n < N) {
        float at = 0.f, ar = 0.f;
        #pragma unroll
        for (int k = 0; k < 48; ++k) {
            float h = sH[nl * 48 + k];
            at = fmaf(h, sWrel[k * 16 + j], at);
            ar = fmaf(h, sWroot[k * 16 + j], ar);
        }
        g_ws[oT3 + (size_t)n * 16 + j] = at;
        out[(size_t)n * 16 + j] = ar + b[j] + ax[(size_t)n * 16 + j];
    }
}

extern "C" void kernel_launch(void* const* d_in, const int* in_sizes, int n_in,
                              void* d_out, int out_size, void* d_ws, size_t ws_size,
                              hipStream_t stream) {
    const float* x     = (const float*)d_in[0];
    const int*   edge  = (const int*)d_in[1];
    const float* ax    = (const float*)d_in[2];
    const float* lf    = (const float*)d_in[3];
    const float* W1rel = (const float*)d_in[4];
    const float* b1    = (const float*)d_in[5];
    const float* W1root= (const float*)d_in[6];
    const float* W2rel = (const float*)d_in[7];
    const float* b2    = (const float*)d_in[8];
    const float* W2root= (const float*)d_in[9];
    const float* W3rel = (const float*)d_in[10];
    const float* b3    = (const float*)d_in[11];
    const float* W3root= (const float*)d_in[12];
    float* out = (float*)d_out;

    const int N = in_sizes[0] / 48;
    const int E = in_sizes[1] / 2;

    const size_t oT1 = 0;
    const size_t oR1 = (size_t)N * 32;
    const size_t oH1 = (size_t)N * 64;
    const size_t oT2 = (size_t)N * 96;
    const size_t oR2 = (size_t)N * 144;
    const size_t oH2 = (size_t)N * 192;
    const size_t oT3 = (size_t)N * 240;

    const int eb = (E + 255) / 256;

    // CSR build (graph identical across layers — build once per call)
    k_zero_cnt<<<(N + 255) / 256, 256, 0, stream>>>(N);
    k_hist<<<eb, 256, 0, stream>>>(edge, E);
    k_scan<<<1, SCAN_T, 0, stream>>>(N);
    k_scatter<<<eb, 256, 0, stream>>>(edge, E);

    // Layer 1
    k_l1_transform<<<(N + 7) / 8, 256, 0, stream>>>(x, ax, W1rel, W1root, b1, N, oT1, oR1);
    k_gather_relu<32><<<(unsigned)(((size_t)N * 8 + 255) / 256), 256, 0, stream>>>(oT1, oR1, oH1, N);
    // Layer 2
    k_l2_transform<<<(N + 7) / 8, 384, 0, stream>>>(lf, W2rel, W2root, b2, N, oH1, oT2, oR2);
    k_gather_relu<48><<<(unsigned)(((size_t)N * 12 + 255) / 256), 256, 0, stream>>>(oT2, oR2, oH2, N);
    // Layer 3
    k_l3_transform<<<(N + 15) / 16, 256, 0, stream>>>(ax, W3rel, W3root, b3, N, oH2, oT3, out);
    k_gather_out<<<(unsigned)(((size_t)N * 4 + 255) / 256), 256, 0, stream>>>(oT3, out, N);
}

// Round 3
// 525.725 us; speedup vs baseline: 1.7309x; 1.4216x over previous
//
#include <hip/hip_runtime.h>

#define NODES_MAX 100000
#define EDGES_MAX 1600000
#define SCAN_CHUNK 1024  // elements per block in local scan

// Float scratch: N*256 floats @ N=100000 -> 102.4 MB
// layout (float offsets): t1:0  r1:N*32  h1:N*64  t2:N*96  r2:N*144  h2:N*192  t3:N*240
__device__ float g_ws[(size_t)NODES_MAX * 256];
__device__ int g_rowptr[NODES_MAX + 1];
__device__ int g_cnt[NODES_MAX];      // deg -> cursor
__device__ int g_csr[EDGES_MAX];      // src node id grouped by dst
__device__ int g_bsum[(NODES_MAX + SCAN_CHUNK - 1) / SCAN_CHUNK + 1];

// ---------------- CSR build ----------------
__global__ __launch_bounds__(256) void k_zero_cnt(int N) {
    int i = blockIdx.x * 256 + threadIdx.x;
    if (i < N) g_cnt[i] = 0;
}

__global__ __launch_bounds__(256) void k_hist(const int* __restrict__ edge, int E) {
    int e = blockIdx.x * 256 + threadIdx.x;
    if (e < E) atomicAdd(&g_cnt[edge[E + e]], 1);
}

// Multi-block scan, step 1: per-block local exclusive prefix + block totals.
// Block covers SCAN_CHUNK elements; 256 threads x 4 elements each.
__global__ __launch_bounds__(256) void k_scan_local(int N) {
    __shared__ int ssum[256];
    const int tid = threadIdx.x;
    const int base = blockIdx.x * SCAN_CHUNK + tid * 4;
    int v0 = (base + 0 < N) ? g_cnt[base + 0] : 0;
    int v1 = (base + 1 < N) ? g_cnt[base + 1] : 0;
    int v2 = (base + 2 < N) ? g_cnt[base + 2] : 0;
    int v3 = (base + 3 < N) ? g_cnt[base + 3] : 0;
    int s = v0 + v1 + v2 + v3;
    ssum[tid] = s;
    __syncthreads();
    for (int off = 1; off < 256; off <<= 1) {
        int v = (tid >= off) ? ssum[tid - off] : 0;
        __syncthreads();
        ssum[tid] += v;
        __syncthreads();
    }
    int run = ssum[tid] - s;  // thread-exclusive prefix within block
    if (base + 0 < N) g_rowptr[base + 0] = run;
    run += v0;
    if (base + 1 < N) g_rowptr[base + 1] = run;
    run += v1;
    if (base + 2 < N) g_rowptr[base + 2] = run;
    run += v2;
    if (base + 3 < N) g_rowptr[base + 3] = run;
    if (tid == 255) g_bsum[blockIdx.x] = ssum[255];  // block total
}

// Step 2: exclusive scan of block totals (nb <= 1024), single block.
__global__ __launch_bounds__(1024) void k_scan_bsums(int nb) {
    __shared__ int ssum[1024];
    const int tid = threadIdx.x;
    int s = (tid < nb) ? g_bsum[tid] : 0;
    ssum[tid] = s;
    __syncthreads();
    for (int off = 1; off < 1024; off <<= 1) {
        int v = (tid >= off) ? ssum[tid - off] : 0;
        __syncthreads();
        ssum[tid] += v;
        __syncthreads();
    }
    if (tid < nb) g_bsum[tid] = ssum[tid] - s;  // exclusive block offset
}

// Step 3: add block offsets; produce rowptr + cursor init.
__global__ __launch_bounds__(256) void k_scan_add(int N, int E) {
    int i = blockIdx.x * 256 + threadIdx.x;
    if (i < N) {
        int v = g_rowptr[i] + g_bsum[i / SCAN_CHUNK];
        g_rowptr[i] = v;
        g_cnt[i] = v;
    }
    if (i == 0) g_rowptr[N] = E;
}

__global__ __launch_bounds__(256) void k_scatter(const int* __restrict__ edge, int E) {
    int e = blockIdx.x * 256 + threadIdx.x;
    if (e < E) {
        int s = edge[e], d = edge[E + e];
        int pos = atomicAdd(&g_cnt[d], 1);
        g_csr[pos] = s;
    }
}

// ---------------- gathers ----------------
// h[node] = relu( sum_{in-edges} t[src] + r[node] )
template <int F>
__global__ __launch_bounds__(256) void k_gather_relu(size_t oT, size_t oR, size_t oH, int N) {
    constexpr int F4 = F / 4;
    int tid = blockIdx.x * 256 + threadIdx.x;
    int node = tid / F4, c4 = tid % F4;
    if (node >= N) return;
    const float* __restrict__ t = &g_ws[oT];
    int start = g_rowptr[node], end = g_rowptr[node + 1];
    float4 s = {0.f, 0.f, 0.f, 0.f};
    for (int j = start; j < end; ++j) {
        int sn = g_csr[j];
        const float4 v = *(const float4*)&t[(size_t)sn * F + c4 * 4];
        s.x += v.x; s.y += v.y; s.z += v.z; s.w += v.w;
    }
    const float4 rv = *(const float4*)&g_ws[oR + (size_t)node * F + c4 * 4];
    float4 o;
    o.x = fmaxf(s.x + rv.x, 0.f);
    o.y = fmaxf(s.y + rv.y, 0.f);
    o.z = fmaxf(s.z + rv.z, 0.f);
    o.w = fmaxf(s.w + rv.w, 0.f);
    *(float4*)&g_ws[oH + (size_t)node * F + c4 * 4] = o;
}

// out[node] += sum_{in-edges} t3[src]   (out pre-seeded with root+bias+ax)
__global__ __launch_bounds__(256) void k_gather_out(size_t oT, float* __restrict__ out, int N) {
    constexpr int F = 16, F4 = 4;
    int tid = blockIdx.x * 256 + threadIdx.x;
    int node = tid / F4, c4 = tid % F4;
    if (node >= N) return;
    const float* __restrict__ t = &g_ws[oT];
    int start = g_rowptr[node], end = g_rowptr[node + 1];
    float4 s = {0.f, 0.f, 0.f, 0.f};
    for (int j = start; j < end; ++j) {
        int sn = g_csr[j];
        const float4 v = *(const float4*)&t[(size_t)sn * F + c4 * 4];
        s.x += v.x; s.y += v.y; s.z += v.z; s.w += v.w;
    }
    float4* op = (float4*)&out[(size_t)node * F + c4 * 4];
    float4 ov = *op;
    ov.x += s.x; ov.y += s.y; ov.z += s.z; ov.w += s.w;
    *op = ov;
}

// ---------------- transforms ----------------
__global__ __launch_bounds__(256) void k_l1_transform(
        const float* __restrict__ x, const float* __restrict__ ax,
        const float* __restrict__ Wrel, const float* __restrict__ Wroot,
        const float* __restrict__ b, int N, size_t oT1, size_t oR1) {
    __shared__ float sWrel[64 * 32];
    __shared__ float sWroot[64 * 32];
    __shared__ float sH[8 * 64];
    const int tid = threadIdx.x;
    for (int i = tid; i < 64 * 32; i += 256) { sWrel[i] = Wrel[i]; sWroot[i] = Wroot[i]; }
    const int n0 = blockIdx.x * 8;
    for (int i = tid; i < 8 * 64; i += 256) {
        int nl = i >> 6, k = i & 63, n = n0 + nl;
        float v = 0.f;
        if (n < N) v = (k < 48) ? x[(size_t)n * 48 + k] : ax[(size_t)n * 16 + (k - 48)];
        sH[i] = v;
    }
    __syncthreads();
    const int nl = tid >> 5, j = tid & 31, n = n0 + nl;
    if (n < N) {
        float at = 0.f, ar = 0.f;
        #pragma unroll
        for (int k = 0; k < 64; ++k) {
            float h = sH[nl * 64 + k];
            at = fmaf(h, sWrel[k * 32 + j], at);
            ar = fmaf(h, sWroot[k * 32 + j], ar);
        }
        g_ws[oT1 + (size_t)n * 32 + j] = at;
        g_ws[oR1 + (size_t)n * 32 + j] = ar + b[j];
    }
}

__global__ __launch_bounds__(384) void k_l2_transform(
        const float* __restrict__ lf,
        const float* __restrict__ Wrel, const float* __restrict__ Wroot,
        const float* __restrict__ b, int N,
        size_t oH1, size_t oT2, size_t oR2) {
    __shared__ float sWrel[48 * 48];
    __shared__ float sWroot[48 * 48];
    __shared__ float sH[8 * 48];
    const int tid = threadIdx.x;
    for (int i = tid; i < 48 * 48; i += 384) { sWrel[i] = Wrel[i]; sWroot[i] = Wroot[i]; }
    const int n0 = blockIdx.x * 8;
    {
        int nl = tid / 48, k = tid % 48, n = n0 + nl;  // 384 == 8*48
        float v = 0.f;
        if (n < N) {
            v = (k < 32) ? g_ws[oH1 + (size_t)n * 32 + k]
                         : lf[(size_t)n * 16 + (k - 32)];
        }
        sH[tid] = v;
    }
    __syncthreads();
    const int nl = tid / 48, j = tid % 48, n = n0 + nl;
    if (n < N) {
        float at = 0.f, ar = 0.f;
        #pragma unroll
        for (int k = 0; k < 48; ++k) {
            float h = sH[nl * 48 + k];
            at = fmaf(h, sWrel[k * 48 + j], at);
            ar = fmaf(h, sWroot[k * 48 + j], ar);
        }
        g_ws[oT2 + (size_t)n * 48 + j] = at;
        g_ws[oR2 + (size_t)n * 48 + j] = ar + b[j];
    }
}

__global__ __launch_bounds__(256) void k_l3_transform(
        const float* __restrict__ ax,
        const float* __restrict__ Wrel, const float* __restrict__ Wroot,
        const float* __restrict__ b, int N,
        size_t oH2, size_t oT3, float* __restrict__ out) {
    __shared__ float sWrel[48 * 16];
    __shared__ float sWroot[48 * 16];
    __shared__ float sH[16 * 48];
    const int tid = threadIdx.x;
    for (int i = tid; i < 48 * 16; i += 256) { sWrel[i] = Wrel[i]; sWroot[i] = Wroot[i]; }
    const int n0 = blockIdx.x * 16;
    for (int i = tid; i < 16 * 48; i += 256) {
        int nl = i / 48, k = i % 48, n = n0 + nl;
        sH[i] = (n < N) ? g_ws[oH2 + (size_t)n * 48 + k] : 0.f;
    }
    __syncthreads();
    const int nl = tid >> 4, j = tid & 15, n = n0 + nl;
    if (n < N) {
        float at = 0.f, ar = 0.f;
        #pragma unroll
        for (int k = 0; k < 48; ++k) {
            float h = sH[nl * 48 + k];
            at = fmaf(h, sWrel[k * 16 + j], at);
            ar = fmaf(h, sWroot[k * 16 + j], ar);
        }
        g_ws[oT3 + (size_t)n * 16 + j] = at;
        out[(size_t)n * 16 + j] = ar + b[j] + ax[(size_t)n * 16 + j];
    }
}

extern "C" void kernel_launch(void* const* d_in, const int* in_sizes, int n_in,
                              void* d_out, int out_size, void* d_ws, size_t ws_size,
                              hipStream_t stream) {
    const float* x     = (const float*)d_in[0];
    const int*   edge  = (const int*)d_in[1];
    const float* ax    = (const float*)d_in[2];
    const float* lf    = (const float*)d_in[3];
    const float* W1rel = (const float*)d_in[4];
    const float* b1    = (const float*)d_in[5];
    const float* W1root= (const float*)d_in[6];
    const float* W2rel = (const float*)d_in[7];
    const float* b2    = (const float*)d_in[8];
    const float* W2root= (const float*)d_in[9];
    const float* W3rel = (const float*)d_in[10];
    const float* b3    = (const float*)d_in[11];
    const float* W3root= (const float*)d_in[12];
    float* out = (float*)d_out;

    const int N = in_sizes[0] / 48;
    const int E = in_sizes[1] / 2;

    const size_t oT1 = 0;
    const size_t oR1 = (size_t)N * 32;
    const size_t oH1 = (size_t)N * 64;
    const size_t oT2 = (size_t)N * 96;
    const size_t oR2 = (size_t)N * 144;
    const size_t oH2 = (size_t)N * 192;
    const size_t oT3 = (size_t)N * 240;

    const int eb = (E + 255) / 256;
    const int nb = (N + SCAN_CHUNK - 1) / SCAN_CHUNK;

    // CSR build (graph identical across layers — build once per call)
    k_zero_cnt<<<(N + 255) / 256, 256, 0, stream>>>(N);
    k_hist<<<eb, 256, 0, stream>>>(edge, E);
    k_scan_local<<<nb, 256, 0, stream>>>(N);
    k_scan_bsums<<<1, 1024, 0, stream>>>(nb);
    k_scan_add<<<(N + 255) / 256, 256, 0, stream>>>(N, E);
    k_scatter<<<eb, 256, 0, stream>>>(edge, E);

    // Layer 1
    k_l1_transform<<<(N + 7) / 8, 256, 0, stream>>>(x, ax, W1rel, W1root, b1, N, oT1, oR1);
    k_gather_relu<32><<<(unsigned)(((size_t)N * 8 + 255) / 256), 256, 0, stream>>>(oT1, oR1, oH1, N);
    // Layer 2
    k_l2_transform<<<(N + 7) / 8, 384, 0, stream>>>(lf, W2rel, W2root, b2, N, oH1, oT2, oR2);
    k_gather_relu<48><<<(unsigned)(((size_t)N * 12 + 255) / 256), 256, 0, stream>>>(oT2, oR2, oH2, N);
    // Layer 3
    k_l3_transform<<<(N + 15) / 16, 256, 0, stream>>>(ax, W3rel, W3root, b3, N, oH2, oT3, out);
    k_gather_out<<<(unsigned)(((size_t)N * 4 + 255) / 256), 256, 0, stream>>>(oT3, out, N);
}